// Round 12
// baseline (323.299 us; speedup 1.0000x reference)
//
#include <hip/hip_runtime.h>
#include <hip/hip_bf16.h>

typedef unsigned short u16;
typedef unsigned int u32;
typedef __attribute__((ext_vector_type(8))) short bf16x8;
typedef __attribute__((ext_vector_type(4))) float f32x4;
typedef __attribute__((ext_vector_type(2))) float f32x2;
typedef __attribute__((ext_vector_type(4))) unsigned short u16x4;

#define NBLK 256   // 256 blocks x 512 rows = 131072 rows; 1 block/CU (LDS-capped)

// shared_exp = floor(log2(amax)) - 8 ; scale = 2^shared_exp (power of two)
__device__ __forceinline__ void block_scale(float amax, float& scale, float& inv_scale) {
    int be = (int)(__float_as_uint(amax) >> 23);   // biased exponent, amax >= 0
    be = be < 8 ? 8 : be;                          // tiny/zero blocks quantize to 0 anyway
    scale     = __uint_as_float((unsigned)(be - 8) << 23);   // 2^(be-135)
    inv_scale = __uint_as_float((unsigned)(262 - be) << 23); // 2^(135-be)
}

#if __has_builtin(__builtin_amdgcn_cvt_pk_fp8_f32) && __has_builtin(__builtin_amdgcn_cvt_pk_f32_fp8)
#define HAS_HW_FP8 1
#else
#define HAS_HW_FP8 0
#endif

#if !HAS_HW_FP8
// Fallback: exact bit-math e4m3 RNE (verified in round 0)
__device__ __forceinline__ float mx_e4m3(float x, float inv_scale, float scale) {
    float v  = x * inv_scale;
    float av = fabsf(v);
    int e = (int)(__float_as_uint(av) >> 23) - 127;
    e = e < -6 ? -6 : (e > 8 ? 8 : e);
    float qs = __uint_as_float((unsigned)(130 - e) << 23);
    float qm = __uint_as_float((unsigned)(124 + e) << 23);
    float q  = fminf(rintf(av * qs) * qm, 448.0f);
    return copysignf(q, v) * scale;
}
#endif

// Quantize 4 elems to e4m3 grid (RNE, saturate 448), return bf16 bits of value*scale.
__device__ __forceinline__ u16x4 quant4(float4 v, float inv, float sc) {
    u16x4 r;
#if HAS_HW_FP8
    float a = fminf(fmaxf(v.x * inv, -448.f), 448.f);
    float b = fminf(fmaxf(v.y * inv, -448.f), 448.f);
    float c = fminf(fmaxf(v.z * inv, -448.f), 448.f);
    float d = fminf(fmaxf(v.w * inv, -448.f), 448.f);
    int p = __builtin_amdgcn_cvt_pk_fp8_f32(a, b, 0, false);   // RNE f32->e4m3 (OCP)
    p     = __builtin_amdgcn_cvt_pk_fp8_f32(c, d, p, true);
    f32x2 lo = __builtin_amdgcn_cvt_pk_f32_fp8(p, false);      // exact e4m3->f32
    f32x2 hi = __builtin_amdgcn_cvt_pk_f32_fp8(p, true);
    r.x = (u16)(__float_as_uint(lo[0] * sc) >> 16);
    r.y = (u16)(__float_as_uint(lo[1] * sc) >> 16);
    r.z = (u16)(__float_as_uint(hi[0] * sc) >> 16);
    r.w = (u16)(__float_as_uint(hi[1] * sc) >> 16);
#else
    r.x = (u16)(__float_as_uint(mx_e4m3(v.x, inv, sc)) >> 16);
    r.y = (u16)(__float_as_uint(mx_e4m3(v.y, inv, sc)) >> 16);
    r.z = (u16)(__float_as_uint(mx_e4m3(v.z, inv, sc)) >> 16);
    r.w = (u16)(__float_as_uint(mx_e4m3(v.w, inv, sc)) >> 16);
#endif
    return r;
}

// Quantize 256x256 weight to bf16 fake-quant, stored TRANSPOSED: Bq[n*256+k].
__global__ void wq_kernel(const float* __restrict__ W, u16* __restrict__ Bq) {
    const int t  = blockIdx.x * blockDim.x + threadIdx.x;
    const int f  = t * 4;
    const int k  = f >> 8;
    const int n0 = f & 255;
    const float4 v = *(const float4*)(W + f);
    float am = fmaxf(fmaxf(fabsf(v.x), fabsf(v.y)), fmaxf(fabsf(v.z), fabsf(v.w)));
    am = fmaxf(am, __shfl_xor(am, 1));   // 8 lanes x 4 elems = one 32-elem MX block
    am = fmaxf(am, __shfl_xor(am, 2));
    am = fmaxf(am, __shfl_xor(am, 4));
    float sc, inv; block_scale(am, sc, inv);
    u16x4 q = quant4(v, inv, sc);
    Bq[(size_t)(n0 + 0) * 256 + k] = q.x;
    Bq[(size_t)(n0 + 1) * 256 + k] = q.y;
    Bq[(size_t)(n0 + 2) * 256 + k] = q.z;
    Bq[(size_t)(n0 + 3) * 256 + k] = q.w;
}

// Barrier-free streaming GEMM, register-budgeted for <=~128 VGPRs:
//  - 1 block (8 waves) per CU; B (128 KB bf16 [n][k]) + bias staged in LDS once,
//    ONE __syncthreads, then no barriers (waves fully independent, stagger keeps
//    HBM demand continuous).
//  - per 16-row strip: 16 float4 X loads (1-deep; partial vmcnt waits pipeline
//    quant), in-register quant (lane lr = row, k = ks*32+lg*8; amax via
//    shfl_xor 16/32 across the 4 lg-lanes of a row = one 32-elem MX block),
//    then MFMA in TWO col-halves of 8 ct (acc[8] live, not 16) vs LDS B.
//  - wave w takes strips s*8+w: block writes stay in a ~128-row window
//    (compact L2 write frontier; R11's WRITE amplification fix).
__global__ void __launch_bounds__(512, 1)
mx_gemm(const float* __restrict__ X, const u16* __restrict__ Bq,
        const float* __restrict__ bias, float* __restrict__ out)
{
    __shared__ u16   Bs[256 * 256];   // 128 KB, rows XOR-swizzled by (n&7)<<4
    __shared__ float bs[256];         // bias
    const int tid = threadIdx.x;
    const int w   = tid >> 6;
    const int l   = tid & 63;
    const int lr  = l & 15;
    const int lg  = l >> 4;

    // ---- one-time prologue: B -> LDS swizzled; bias -> LDS ----
    #pragma unroll
    for (int i = 0; i < 16; ++i) {
        const u32 g = (u32)(tid + i * 512) * 16;        // linear byte offset in Bq
        const u32 d = g ^ (((g >> 9) & 7) << 4);        // XOR bits 4..6 by n&7
        *(bf16x8*)((char*)Bs + d) = *(const bf16x8*)((const char*)Bq + g);
    }
    if (tid < 256) bs[tid] = bias[tid];
    __syncthreads();                                    // the ONLY barrier

    const u32   swz = (u32)(lr & 7) << 4;
    const char* BsB = (const char*)Bs;

    #pragma unroll 1
    for (int s = 0; s < 4; ++s) {
        const size_t row0 = (size_t)blockIdx.x * 512 + (size_t)(s * 8 + w) * 16;
        const float* xp = X + (row0 + lr) * 256 + lg * 8;

        // ---- 16 strip loads (issued back-to-back; compiler waits partially) ----
        float4 xv[16];
        #pragma unroll
        for (int kp = 0; kp < 8; ++kp) {
            xv[2 * kp]     = *(const float4*)(xp + kp * 32);
            xv[2 * kp + 1] = *(const float4*)(xp + kp * 32 + 4);
        }

        // ---- quantize in-register: xv dies into af (peak ~100 VGPR) ----
        bf16x8 af[8];
        #pragma unroll
        for (int ks = 0; ks < 8; ++ks) {
            const float4 v0 = xv[2 * ks], v1 = xv[2 * ks + 1];
            float am = fmaxf(fmaxf(fabsf(v0.x), fabsf(v0.y)), fmaxf(fabsf(v0.z), fabsf(v0.w)));
            am = fmaxf(am, fmaxf(fmaxf(fabsf(v1.x), fabsf(v1.y)), fmaxf(fabsf(v1.z), fabsf(v1.w))));
            am = fmaxf(am, __shfl_xor(am, 16));   // other lg lanes, same row
            am = fmaxf(am, __shfl_xor(am, 32));
            float sc, inv; block_scale(am, sc, inv);
            const u16x4 q0 = quant4(v0, inv, sc);
            const u16x4 q1 = quant4(v1, inv, sc);
            bf16x8 a;
            a[0] = (short)q0.x; a[1] = (short)q0.y; a[2] = (short)q0.z; a[3] = (short)q0.w;
            a[4] = (short)q1.x; a[5] = (short)q1.y; a[6] = (short)q1.z; a[7] = (short)q1.w;
            af[ks] = a;
        }

        // ---- MFMA in two col-halves (acc[8] = 32 VGPRs live, not 64) ----
        float* op = out + (row0 + lr) * 256 + lg * 4;
        #pragma unroll
        for (int h = 0; h < 2; ++h) {
            f32x4 acc[8];
            #pragma unroll
            for (int ct = 0; ct < 8; ++ct)
                acc[ct] = *(const f32x4*)(bs + (h * 8 + ct) * 16 + lg * 4);
            #pragma unroll
            for (int ks = 0; ks < 8; ++ks) {
                #pragma unroll
                for (int ct = 0; ct < 8; ++ct) {
                    const u32 off = ((u32)(((h * 8 + ct) * 16 + lr) * 512 + ks * 64 + lg * 16)) ^ swz;
                    const bf16x8 bf = *(const bf16x8*)(BsB + off);
                    acc[ct] = __builtin_amdgcn_mfma_f32_16x16x32_bf16(bf, af[ks], acc[ct], 0, 0, 0);
                }
            }
            #pragma unroll
            for (int ct = 0; ct < 8; ++ct)
                *(f32x4*)(op + (h * 8 + ct) * 16) = acc[ct];
        }
    }
}

extern "C" void kernel_launch(void* const* d_in, const int* in_sizes, int n_in,
                              void* d_out, int out_size, void* d_ws, size_t ws_size,
                              hipStream_t stream) {
    const float* x    = (const float*)d_in[0];
    const float* wk   = (const float*)d_in[1];
    const float* bias = (const float*)d_in[2];
    float* out = (float*)d_out;
    u16* Bq    = (u16*)d_ws;                  // 256*256 bf16 = 128 KB scratch
    wq_kernel<<<64, 256, 0, stream>>>(wk, Bq);
    mx_gemm<<<NBLK, 512, 0, stream>>>(x, Bq, bias, out);
}

// Round 13
// 62.447 us; speedup vs baseline: 5.1771x; 5.1771x over previous
//
#include <hip/hip_runtime.h>
#include <hip/hip_bf16.h>

typedef unsigned short u16;
typedef unsigned int u32;
typedef __attribute__((ext_vector_type(8))) short bf16x8;
typedef __attribute__((ext_vector_type(4))) float f32x4;
typedef __attribute__((ext_vector_type(2))) float f32x2;
typedef __attribute__((ext_vector_type(4))) unsigned short u16x4;

#define NBLK 256   // 256 blocks x 512 rows = 131072 rows; 1 block/CU (LDS-capped)

// shared_exp = floor(log2(amax)) - 8 ; scale = 2^shared_exp (power of two)
__device__ __forceinline__ void block_scale(float amax, float& scale, float& inv_scale) {
    int be = (int)(__float_as_uint(amax) >> 23);   // biased exponent, amax >= 0
    be = be < 8 ? 8 : be;                          // tiny/zero blocks quantize to 0 anyway
    scale     = __uint_as_float((unsigned)(be - 8) << 23);   // 2^(be-135)
    inv_scale = __uint_as_float((unsigned)(262 - be) << 23); // 2^(135-be)
}

#if __has_builtin(__builtin_amdgcn_cvt_pk_fp8_f32) && __has_builtin(__builtin_amdgcn_cvt_pk_f32_fp8)
#define HAS_HW_FP8 1
#else
#define HAS_HW_FP8 0
#endif

#if !HAS_HW_FP8
// Fallback: exact bit-math e4m3 RNE (verified in round 0)
__device__ __forceinline__ float mx_e4m3(float x, float inv_scale, float scale) {
    float v  = x * inv_scale;
    float av = fabsf(v);
    int e = (int)(__float_as_uint(av) >> 23) - 127;
    e = e < -6 ? -6 : (e > 8 ? 8 : e);
    float qs = __uint_as_float((unsigned)(130 - e) << 23);
    float qm = __uint_as_float((unsigned)(124 + e) << 23);
    float q  = fminf(rintf(av * qs) * qm, 448.0f);
    return copysignf(q, v) * scale;
}
#endif

// Quantize 4 elems to e4m3 grid (RNE, saturate 448), return bf16 bits of value*scale.
__device__ __forceinline__ u16x4 quant4(float4 v, float inv, float sc) {
    u16x4 r;
#if HAS_HW_FP8
    float a = fminf(fmaxf(v.x * inv, -448.f), 448.f);
    float b = fminf(fmaxf(v.y * inv, -448.f), 448.f);
    float c = fminf(fmaxf(v.z * inv, -448.f), 448.f);
    float d = fminf(fmaxf(v.w * inv, -448.f), 448.f);
    int p = __builtin_amdgcn_cvt_pk_fp8_f32(a, b, 0, false);   // RNE f32->e4m3 (OCP)
    p     = __builtin_amdgcn_cvt_pk_fp8_f32(c, d, p, true);
    f32x2 lo = __builtin_amdgcn_cvt_pk_f32_fp8(p, false);      // exact e4m3->f32
    f32x2 hi = __builtin_amdgcn_cvt_pk_f32_fp8(p, true);
    r.x = (u16)(__float_as_uint(lo[0] * sc) >> 16);
    r.y = (u16)(__float_as_uint(lo[1] * sc) >> 16);
    r.z = (u16)(__float_as_uint(hi[0] * sc) >> 16);
    r.w = (u16)(__float_as_uint(hi[1] * sc) >> 16);
#else
    r.x = (u16)(__float_as_uint(mx_e4m3(v.x, inv, sc)) >> 16);
    r.y = (u16)(__float_as_uint(mx_e4m3(v.y, inv, sc)) >> 16);
    r.z = (u16)(__float_as_uint(mx_e4m3(v.z, inv, sc)) >> 16);
    r.w = (u16)(__float_as_uint(mx_e4m3(v.w, inv, sc)) >> 16);
#endif
    return r;
}

// Quantize 256x256 weight to bf16 fake-quant, stored TRANSPOSED: Bq[n*256+k].
__global__ void wq_kernel(const float* __restrict__ W, u16* __restrict__ Bq) {
    const int t  = blockIdx.x * blockDim.x + threadIdx.x;
    const int f  = t * 4;
    const int k  = f >> 8;
    const int n0 = f & 255;
    const float4 v = *(const float4*)(W + f);
    float am = fmaxf(fmaxf(fabsf(v.x), fabsf(v.y)), fmaxf(fabsf(v.z), fabsf(v.w)));
    am = fmaxf(am, __shfl_xor(am, 1));   // 8 lanes x 4 elems = one 32-elem MX block
    am = fmaxf(am, __shfl_xor(am, 2));
    am = fmaxf(am, __shfl_xor(am, 4));
    float sc, inv; block_scale(am, sc, inv);
    u16x4 q = quant4(v, inv, sc);
    Bq[(size_t)(n0 + 0) * 256 + k] = q.x;
    Bq[(size_t)(n0 + 1) * 256 + k] = q.y;
    Bq[(size_t)(n0 + 2) * 256 + k] = q.z;
    Bq[(size_t)(n0 + 3) * 256 + k] = q.w;
}

// Whole-B-in-LDS + pacing-barrier streaming GEMM:
//  - 1 block (8 waves) per CU; B (128 KB bf16 [n][k], XOR-swizzled) + bias staged
//    in LDS once, one __syncthreads, then 4 strips of 128 rows.
//  - per strip: each wave owns 16 rows. 16 float4 X loads issued back-to-back
//    right after the barrier (per CU: 128 KB queued -> HBM streams the whole
//    iteration; compiler's partial vmcnt waits pipeline the quant per-row),
//    in-register quant to MFMA A-fragments (lane lr = row, k = ks*32 + lg*8;
//    amax via shfl_xor 16/32 = one 32-elem MX block), MFMA in TWO col-halves
//    (acc[8] live) against LDS-resident B, f32x4 stores.
//  - strip ends with a RAW pacing s_barrier: NO waitcnt attached (Bs read-only,
//    X wave-private, stores unordered) -> vmcnt never drained, stores stay in
//    flight, but waves stay within one 128-row frontier (no L2 write thrash).
//  - register peak ~115 by design (xv dies into af before acc lives).
__global__ void __launch_bounds__(512, 1)
mx_gemm(const float* __restrict__ X, const u16* __restrict__ Bq,
        const float* __restrict__ bias, float* __restrict__ out)
{
    __shared__ u16   Bs[256 * 256];   // 128 KB, rows XOR-swizzled by (n&7)<<4
    __shared__ float bs[256];         // bias
    const int tid = threadIdx.x;
    const int w   = tid >> 6;
    const int l   = tid & 63;
    const int lr  = l & 15;
    const int lg  = l >> 4;

    // ---- one-time prologue: B -> LDS swizzled; bias -> LDS ----
    #pragma unroll
    for (int i = 0; i < 16; ++i) {
        const u32 g = (u32)(tid + i * 512) * 16;        // linear byte offset in Bq
        const u32 d = g ^ (((g >> 9) & 7) << 4);        // XOR bits 4..6 by n&7
        *(bf16x8*)((char*)Bs + d) = *(const bf16x8*)((const char*)Bq + g);
    }
    if (tid < 256) bs[tid] = bias[tid];
    __syncthreads();

    const u32   swz = (u32)(lr & 7) << 4;
    const char* BsB = (const char*)Bs;

    #pragma unroll 1
    for (int s = 0; s < 4; ++s) {
        const size_t row0 = (size_t)blockIdx.x * 512 + (size_t)s * 128 + (size_t)w * 16;
        const float* xp = X + (row0 + lr) * 256 + lg * 8;

        // ---- 16 strip loads, issued back-to-back (16 KB in flight per wave) ----
        float4 xv[16];
        #pragma unroll
        for (int kp = 0; kp < 8; ++kp) {
            xv[2 * kp]     = *(const float4*)(xp + kp * 32);
            xv[2 * kp + 1] = *(const float4*)(xp + kp * 32 + 4);
        }

        // ---- quantize in-register: xv dies into af ----
        bf16x8 af[8];
        #pragma unroll
        for (int ks = 0; ks < 8; ++ks) {
            const float4 v0 = xv[2 * ks], v1 = xv[2 * ks + 1];
            float am = fmaxf(fmaxf(fabsf(v0.x), fabsf(v0.y)), fmaxf(fabsf(v0.z), fabsf(v0.w)));
            am = fmaxf(am, fmaxf(fmaxf(fabsf(v1.x), fabsf(v1.y)), fabsf(v1.w) > fabsf(v1.z) ? fabsf(v1.w) : fabsf(v1.z)));
            am = fmaxf(am, __shfl_xor(am, 16));   // other lg lanes, same row
            am = fmaxf(am, __shfl_xor(am, 32));
            float sc, inv; block_scale(am, sc, inv);
            const u16x4 q0 = quant4(v0, inv, sc);
            const u16x4 q1 = quant4(v1, inv, sc);
            bf16x8 a;
            a[0] = (short)q0.x; a[1] = (short)q0.y; a[2] = (short)q0.z; a[3] = (short)q0.w;
            a[4] = (short)q1.x; a[5] = (short)q1.y; a[6] = (short)q1.z; a[7] = (short)q1.w;
            af[ks] = a;
        }

        // ---- MFMA in two col-halves (acc[8] live) vs LDS-resident B ----
        float* op = out + (row0 + lr) * 256 + lg * 4;
        #pragma unroll
        for (int h = 0; h < 2; ++h) {
            f32x4 acc[8];
            #pragma unroll
            for (int ct = 0; ct < 8; ++ct)
                acc[ct] = *(const f32x4*)(bs + (h * 8 + ct) * 16 + lg * 4);
            #pragma unroll
            for (int ks = 0; ks < 8; ++ks) {
                #pragma unroll
                for (int ct = 0; ct < 8; ++ct) {
                    const u32 off = ((u32)(((h * 8 + ct) * 16 + lr) * 512 + ks * 64 + lg * 16)) ^ swz;
                    const bf16x8 bf = *(const bf16x8*)(BsB + off);
                    acc[ct] = __builtin_amdgcn_mfma_f32_16x16x32_bf16(bf, af[ks], acc[ct], 0, 0, 0);
                }
            }
            #pragma unroll
            for (int ct = 0; ct < 8; ++ct)
                *(f32x4*)(op + (h * 8 + ct) * 16) = acc[ct];
        }

        // ---- pure pacing barrier: no waitcnt, vmcnt stays in flight ----
        if (s < 3) __builtin_amdgcn_s_barrier();
    }
}

extern "C" void kernel_launch(void* const* d_in, const int* in_sizes, int n_in,
                              void* d_out, int out_size, void* d_ws, size_t ws_size,
                              hipStream_t stream) {
    const float* x    = (const float*)d_in[0];
    const float* wk   = (const float*)d_in[1];
    const float* bias = (const float*)d_in[2];
    float* out = (float*)d_out;
    u16* Bq    = (u16*)d_ws;                  // 256*256 bf16 = 128 KB scratch
    wq_kernel<<<64, 256, 0, stream>>>(wk, Bq);
    mx_gemm<<<NBLK, 512, 0, stream>>>(x, Bq, bias, out);
}